// Round 4
// baseline (389.846 us; speedup 1.0000x reference)
//
#include <hip/hip_runtime.h>
#include <hip/hip_bf16.h>

#define NN 169
#define NE 5408
#define F 1024
#define NPIX (NN * F)  // 173056

// ---------------------------------------------------------------------------
// 1) segment_sum: h[dst[e]] += input[src[e]]   grid (169, 4)
// ---------------------------------------------------------------------------
__global__ __launch_bounds__(256) void segsum_kernel(
    const float* __restrict__ input, const int* __restrict__ src,
    const int* __restrict__ dst, float* __restrict__ hsum) {
  __shared__ int s_list[NE];
  __shared__ int s_count;
  const int node = blockIdx.x;
  const int fbase = blockIdx.y * 256;
  const int tid = threadIdx.x;
  if (tid == 0) s_count = 0;
  __syncthreads();
  for (int e = tid; e < NE; e += 256) {
    if (dst[e] == node) {
      int p = atomicAdd(&s_count, 1);
      s_list[p] = src[e];
    }
  }
  __syncthreads();
  const int cnt = s_count;
  const int f = fbase + tid;
  float acc = 0.f;
  for (int i = 0; i < cnt; ++i) acc += input[s_list[i] * F + f];
  hsum[node * F + f] = acc;
}

// ---------------------------------------------------------------------------
// 2) gemm split-K (BM=32, BN=64, 8 chunks of 128)  grid (16,6,8)
// ---------------------------------------------------------------------------
#define KSPLIT 8
#define KCHUNK (1024 / KSPLIT)
__global__ __launch_bounds__(256) void gemm_kernel(
    const float* __restrict__ A, const float* __restrict__ W,
    float* __restrict__ gpart) {
  __shared__ float As[16][33];
  __shared__ float Bs[16][68];
  const int n0 = blockIdx.x * 64;
  const int m0 = blockIdx.y * 32;
  const int kz = blockIdx.z;
  const int tid = threadIdx.x;
  const int tx = tid & 15;
  const int ty = tid >> 4;
  const int ar = tid >> 3, ak = (tid & 7) * 2;
  const int br = tid >> 2, bk = (tid & 3) * 4;
  float acc[2][4] = {};
  for (int k0 = kz * KCHUNK; k0 < (kz + 1) * KCHUNK; k0 += 16) {
    float2 av = make_float2(0.f, 0.f);
    if (m0 + ar < NN)
      av = *reinterpret_cast<const float2*>(&A[(m0 + ar) * F + k0 + ak]);
    As[ak][ar] = av.x; As[ak + 1][ar] = av.y;
    float4 bv = *reinterpret_cast<const float4*>(&W[(n0 + br) * F + k0 + bk]);
    Bs[bk][br] = bv.x; Bs[bk + 1][br] = bv.y;
    Bs[bk + 2][br] = bv.z; Bs[bk + 3][br] = bv.w;
    __syncthreads();
#pragma unroll
    for (int k = 0; k < 16; ++k) {
      const float a0 = As[k][ty * 2], a1 = As[k][ty * 2 + 1];
      const float4 b = *reinterpret_cast<const float4*>(&Bs[k][tx * 4]);
      acc[0][0] += a0 * b.x; acc[0][1] += a0 * b.y;
      acc[0][2] += a0 * b.z; acc[0][3] += a0 * b.w;
      acc[1][0] += a1 * b.x; acc[1][1] += a1 * b.y;
      acc[1][2] += a1 * b.z; acc[1][3] += a1 * b.w;
    }
    __syncthreads();
  }
#pragma unroll
  for (int i = 0; i < 2; ++i) {
    const int m = m0 + ty * 2 + i;
    if (m < NN)
      *reinterpret_cast<float4*>(&gpart[kz * NPIX + m * F + n0 + tx * 4]) =
          make_float4(acc[i][0], acc[i][1], acc[i][2], acc[i][3]);
  }
}

__global__ __launch_bounds__(256) void reduce_kernel(
    const float* __restrict__ gpart, const float* __restrict__ bias,
    float* __restrict__ hlin) {
  const int i = blockIdx.x * 256 + threadIdx.x;
  float a = 0.f;
#pragma unroll
  for (int z = 0; z < KSPLIT; ++z) a += gpart[z * NPIX + i];
  hlin[i] = a + bias[i & (F - 1)];
}

// ---------------------------------------------------------------------------
// 3) W2 (32,64,3,3) -> w2t[(ic*9+k)*32 + oc]
// ---------------------------------------------------------------------------
__global__ __launch_bounds__(256) void w2t_kernel(const float* __restrict__ W2,
                                                  float* __restrict__ w2t) {
  const int j = blockIdx.x * 256 + threadIdx.x;
  if (j >= 32 * 64 * 9) return;
  const int oc = j & 31;
  const int t = j >> 5;
  w2t[j] = W2[oc * 576 + t];
}

// ---------------------------------------------------------------------------
// 4) h2init: h2[oc][*] = b2[oc]  (conv2 bias; partials atomicAdd on top)
// ---------------------------------------------------------------------------
__global__ __launch_bounds__(256) void h2init_kernel(const float* __restrict__ b2,
                                                     float* __restrict__ h2) {
  const int oc = blockIdx.y;
  const float v = b2[oc];
  const int i4 = blockIdx.x * 256 + threadIdx.x;  // grid.x*256 == NPIX/4
  reinterpret_cast<float4*>(h2)[oc * (NPIX / 4) + i4] = make_float4(v, v, v, v);
}

// ---------------------------------------------------------------------------
// 5) conv12: fused conv1(1->64)+relu -> conv2 partial (8 ics per block),
//    atomicAdd into h2 (pre-relu). Tile 16 rows x 64 cols; thread = 1 col x
//    4 rows x 32 oc (acc[4][32]). grid (16, 11, 8) = 1408 blocks.
// ---------------------------------------------------------------------------
#define ICB 8  // input channels per block
__global__ __launch_bounds__(256) void conv12_kernel(
    const float* __restrict__ hlin, const float* __restrict__ W1,
    const float* __restrict__ b1, const float* __restrict__ w2t,
    float* __restrict__ h2) {
  __shared__ float s_h[20][68];        // hlin rows y0-2..y0+17, cols x0-2..x0+65
  __shared__ float s_w1[ICB * 9 + 8];  // +8 = b1 chunk
  __shared__ float s_in[4][18][66];    // conv1 out, 4 ics, rows y0-1..y0+16
  __shared__ float s_w2[4 * 9 * 32];
  const int x0 = blockIdx.x * 64;
  const int y0 = blockIdx.y * 16;
  const int cb0 = blockIdx.z * ICB;
  const int tid = threadIdx.x;
  const int lane = tid & 63;   // column
  const int rp = tid >> 6;     // row group: rows y0+4*rp+j

  for (int idx = tid; idx < 1360; idx += 256) {
    const int r = idx / 68, xx = idx - r * 68;
    const int gy = y0 - 2 + r, gx = x0 - 2 + xx;
    s_h[r][xx] = (gy >= 0 && gy < NN && gx >= 0 && gx < 1024)
                     ? hlin[gy * 1024 + gx] : 0.f;
  }
  if (tid < ICB * 9) s_w1[tid] = W1[cb0 * 9 + tid];
  if (tid >= ICB * 9 && tid < ICB * 9 + ICB) s_w1[tid] = b1[cb0 + tid - ICB * 9];

  float acc[4][32];
#pragma unroll
  for (int j = 0; j < 4; ++j)
#pragma unroll
    for (int o = 0; o < 32; ++o) acc[j][o] = 0.f;

  for (int sc = 0; sc < 2; ++sc) {
    const int c4 = sc * 4;
    __syncthreads();  // 1st iter: s_h/s_w1 ready; later: protect s_in/s_w2
    for (int idx = tid; idx < 1152; idx += 256)
      s_w2[idx] = w2t[(cb0 + c4) * 288 + idx];
#pragma unroll
    for (int c = 0; c < 4; ++c) {
      const float wa = s_w1[(c4 + c) * 9 + 0], wb = s_w1[(c4 + c) * 9 + 1],
                  wc = s_w1[(c4 + c) * 9 + 2], wd = s_w1[(c4 + c) * 9 + 3],
                  we = s_w1[(c4 + c) * 9 + 4], wf = s_w1[(c4 + c) * 9 + 5],
                  wg = s_w1[(c4 + c) * 9 + 6], wh = s_w1[(c4 + c) * 9 + 7],
                  wi = s_w1[(c4 + c) * 9 + 8];
      const float bb = s_w1[ICB * 9 + c4 + c];
      for (int idx = tid; idx < 18 * 66; idx += 256) {
        const int r = idx / 66, xx = idx - r * 66;
        const int gy = y0 - 1 + r, gx = x0 - 1 + xx;
        float v = 0.f;
        // FULL guard: conv1 output at padding positions (gy<0, gx<0, gy>=NN,
        // gx>=1024) must be exactly 0 for conv2's SAME padding. Zero-staged
        // s_h only zeroes the *inputs*; conv1 evaluated AT a padding position
        // still sees real in-image rows/cols through its window. (R3 bug.)
        if (gy >= 0 && gy < NN && gx >= 0 && gx < 1024) {
          float a = bb;
          a += s_h[r + 0][xx + 0] * wa + s_h[r + 0][xx + 1] * wb +
               s_h[r + 0][xx + 2] * wc + s_h[r + 1][xx + 0] * wd +
               s_h[r + 1][xx + 1] * we + s_h[r + 1][xx + 2] * wf +
               s_h[r + 2][xx + 0] * wg + s_h[r + 2][xx + 1] * wh +
               s_h[r + 2][xx + 2] * wi;
          v = fmaxf(a, 0.f);
        }
        s_in[c][r][xx] = v;
      }
    }
    __syncthreads();
#pragma unroll
    for (int c = 0; c < 4; ++c) {
#pragma unroll
      for (int ky = 0; ky < 3; ++ky) {
#pragma unroll
        for (int kx = 0; kx < 3; ++kx) {
          const float4* w4 = reinterpret_cast<const float4*>(
              &s_w2[(c * 9 + ky * 3 + kx) * 32]);
          const float4 w0 = w4[0], w1 = w4[1], w2 = w4[2], w3 = w4[3];
          const float4 w4v = w4[4], w5 = w4[5], w6 = w4[6], w7 = w4[7];
#pragma unroll
          for (int j = 0; j < 4; ++j) {
            const float iv = s_in[c][4 * rp + j + ky][lane + kx];
            acc[j][0] += iv * w0.x;  acc[j][1] += iv * w0.y;
            acc[j][2] += iv * w0.z;  acc[j][3] += iv * w0.w;
            acc[j][4] += iv * w1.x;  acc[j][5] += iv * w1.y;
            acc[j][6] += iv * w1.z;  acc[j][7] += iv * w1.w;
            acc[j][8] += iv * w2.x;  acc[j][9] += iv * w2.y;
            acc[j][10] += iv * w2.z; acc[j][11] += iv * w2.w;
            acc[j][12] += iv * w3.x; acc[j][13] += iv * w3.y;
            acc[j][14] += iv * w3.z; acc[j][15] += iv * w3.w;
            acc[j][16] += iv * w4v.x; acc[j][17] += iv * w4v.y;
            acc[j][18] += iv * w4v.z; acc[j][19] += iv * w4v.w;
            acc[j][20] += iv * w5.x; acc[j][21] += iv * w5.y;
            acc[j][22] += iv * w5.z; acc[j][23] += iv * w5.w;
            acc[j][24] += iv * w6.x; acc[j][25] += iv * w6.y;
            acc[j][26] += iv * w6.z; acc[j][27] += iv * w6.w;
            acc[j][28] += iv * w7.x; acc[j][29] += iv * w7.y;
            acc[j][30] += iv * w7.z; acc[j][31] += iv * w7.w;
          }
        }
      }
    }
  }
  // coalesced atomic epilogue: per (j, oc) one 256B wave transaction
  const int x = x0 + lane;
#pragma unroll
  for (int j = 0; j < 4; ++j) {
    const int y = y0 + 4 * rp + j;
    if (y < NN) {
#pragma unroll
      for (int o = 0; o < 32; ++o)
        atomicAdd(&h2[o * NPIX + y * 1024 + x], acc[j][o]);
    }
  }
}

// ---------------------------------------------------------------------------
// 6) conv3 (32->1) + relu -> out.  h2 is pre-relu: relu applied on load.
// ---------------------------------------------------------------------------
__global__ __launch_bounds__(256) void conv3_kernel(
    const float* __restrict__ h2, const float* __restrict__ W3,
    const float* __restrict__ b3, float* __restrict__ out) {
  __shared__ float s_in[32][6][66];
  __shared__ float s_w3[288];
  const int x0 = blockIdx.x * 64;
  const int y0 = blockIdx.y * 4;
  const int tid = threadIdx.x;
  const int ty = tid >> 6, tx = tid & 63;
  for (int idx = tid; idx < 288; idx += 256) s_w3[idx] = W3[idx];
  for (int idx = tid; idx < 32 * 6 * 66; idx += 256) {
    const int c = idx / 396;
    const int rem = idx - c * 396;
    const int r = rem / 66, xx = rem - r * 66;
    const int gy = y0 - 1 + r, gx = x0 - 1 + xx;
    s_in[c][r][xx] = (gy >= 0 && gy < NN && gx >= 0 && gx < 1024)
                         ? fmaxf(h2[c * NPIX + gy * 1024 + gx], 0.f) : 0.f;
  }
  __syncthreads();
  const int y = y0 + ty, x = x0 + tx;
  float acc = b3[0];
  for (int c = 0; c < 32; ++c) {
#pragma unroll
    for (int k = 0; k < 9; ++k)
      acc += s_in[c][ty + k / 3][tx + k % 3] * s_w3[c * 9 + k];
  }
  if (y < NN) out[y * 1024 + x] = fmaxf(acc, 0.f);
}

// ---------------------------------------------------------------------------
extern "C" void kernel_launch(void* const* d_in, const int* in_sizes, int n_in,
                              void* d_out, int out_size, void* d_ws, size_t ws_size,
                              hipStream_t stream) {
  const float* input = (const float*)d_in[0];
  const int*   src   = (const int*)d_in[1];
  const int*   dst   = (const int*)d_in[2];
  const float* W_lin = (const float*)d_in[3];
  const float* b_lin = (const float*)d_in[4];
  const float* W1    = (const float*)d_in[5];
  const float* b1    = (const float*)d_in[6];
  const float* W2    = (const float*)d_in[7];
  const float* b2    = (const float*)d_in[8];
  const float* W3    = (const float*)d_in[9];
  const float* b3    = (const float*)d_in[10];
  float* out = (float*)d_out;

  // ws (floats): hsum | hlin | w2t | h2(32*NPIX)  ~= 23.6 MB
  // gemm partials (8*NPIX) alias h2 (reduce finishes before h2init, same stream)
  float* hsum = (float*)d_ws;
  float* hlin = hsum + NPIX;
  float* w2t  = hlin + NPIX;
  float* h2   = w2t + 64 * 9 * 32;
  float* gpart = h2;

  segsum_kernel<<<dim3(NN, 4), 256, 0, stream>>>(input, src, dst, hsum);
  gemm_kernel<<<dim3(16, 6, KSPLIT), 256, 0, stream>>>(hsum, W_lin, gpart);
  w2t_kernel<<<72, 256, 0, stream>>>(W2, w2t);
  reduce_kernel<<<NPIX / 256, 256, 0, stream>>>(gpart, b_lin, hlin);
  h2init_kernel<<<dim3(NPIX / 4 / 256, 32), 256, 0, stream>>>(b2, h2);
  conv12_kernel<<<dim3(16, 11, ICB), 256, 0, stream>>>(hlin, W1, b1, w2t, h2);
  conv3_kernel<<<dim3(16, 43), 256, 0, stream>>>(h2, W3, b3, out);
}

// Round 5
// 161.661 us; speedup vs baseline: 2.4115x; 2.4115x over previous
//
#include <hip/hip_runtime.h>
#include <hip/hip_bf16.h>

#define NN 169
#define NE 5408
#define F 1024
#define NPIX (NN * F)  // 173056

typedef short short8 __attribute__((ext_vector_type(8)));
typedef float f32x16 __attribute__((ext_vector_type(16)));

// RTNE float -> bf16 (bit-level, no NaN handling needed: values finite)
__device__ __forceinline__ ushort f2bf(float f) {
  uint x = __float_as_uint(f);
  return (ushort)((x + 0x7FFFu + ((x >> 16) & 1u)) >> 16);
}

// ---------------------------------------------------------------------------
// 1) segment_sum   grid (169, 4)
// ---------------------------------------------------------------------------
__global__ __launch_bounds__(256) void segsum_kernel(
    const float* __restrict__ input, const int* __restrict__ src,
    const int* __restrict__ dst, float* __restrict__ hsum) {
  __shared__ int s_list[NE];
  __shared__ int s_count;
  const int node = blockIdx.x;
  const int fbase = blockIdx.y * 256;
  const int tid = threadIdx.x;
  if (tid == 0) s_count = 0;
  __syncthreads();
  for (int e = tid; e < NE; e += 256) {
    if (dst[e] == node) {
      int p = atomicAdd(&s_count, 1);
      s_list[p] = src[e];
    }
  }
  __syncthreads();
  const int cnt = s_count;
  const int f = fbase + tid;
  float acc = 0.f;
  for (int i = 0; i < cnt; ++i) acc += input[s_list[i] * F + f];
  hsum[node * F + f] = acc;
}

// ---------------------------------------------------------------------------
// 2) gemm split-K (BM=32, BN=64, 8 chunks of 128)  grid (16,6,8)
// ---------------------------------------------------------------------------
#define KSPLIT 8
#define KCHUNK (1024 / KSPLIT)
__global__ __launch_bounds__(256) void gemm_kernel(
    const float* __restrict__ A, const float* __restrict__ W,
    float* __restrict__ gpart) {
  __shared__ float As[16][33];
  __shared__ float Bs[16][68];
  const int n0 = blockIdx.x * 64;
  const int m0 = blockIdx.y * 32;
  const int kz = blockIdx.z;
  const int tid = threadIdx.x;
  const int tx = tid & 15;
  const int ty = tid >> 4;
  const int ar = tid >> 3, ak = (tid & 7) * 2;
  const int br = tid >> 2, bk = (tid & 3) * 4;
  float acc[2][4] = {};
  for (int k0 = kz * KCHUNK; k0 < (kz + 1) * KCHUNK; k0 += 16) {
    float2 av = make_float2(0.f, 0.f);
    if (m0 + ar < NN)
      av = *reinterpret_cast<const float2*>(&A[(m0 + ar) * F + k0 + ak]);
    As[ak][ar] = av.x; As[ak + 1][ar] = av.y;
    float4 bv = *reinterpret_cast<const float4*>(&W[(n0 + br) * F + k0 + bk]);
    Bs[bk][br] = bv.x; Bs[bk + 1][br] = bv.y;
    Bs[bk + 2][br] = bv.z; Bs[bk + 3][br] = bv.w;
    __syncthreads();
#pragma unroll
    for (int k = 0; k < 16; ++k) {
      const float a0 = As[k][ty * 2], a1 = As[k][ty * 2 + 1];
      const float4 b = *reinterpret_cast<const float4*>(&Bs[k][tx * 4]);
      acc[0][0] += a0 * b.x; acc[0][1] += a0 * b.y;
      acc[0][2] += a0 * b.z; acc[0][3] += a0 * b.w;
      acc[1][0] += a1 * b.x; acc[1][1] += a1 * b.y;
      acc[1][2] += a1 * b.z; acc[1][3] += a1 * b.w;
    }
    __syncthreads();
  }
#pragma unroll
  for (int i = 0; i < 2; ++i) {
    const int m = m0 + ty * 2 + i;
    if (m < NN)
      *reinterpret_cast<float4*>(&gpart[kz * NPIX + m * F + n0 + tx * 4]) =
          make_float4(acc[i][0], acc[i][1], acc[i][2], acc[i][3]);
  }
}

__global__ __launch_bounds__(256) void reduce_kernel(
    const float* __restrict__ gpart, const float* __restrict__ bias,
    float* __restrict__ hlin) {
  const int i = blockIdx.x * 256 + threadIdx.x;
  float a = 0.f;
#pragma unroll
  for (int z = 0; z < KSPLIT; ++z) a += gpart[z * NPIX + i];
  hlin[i] = a + bias[i & (F - 1)];
}

// ---------------------------------------------------------------------------
// 3) pack W2 (32,64,3,3) into bf16 MFMA B-fragments for 32x32x16:
//    chunk kc = (ky*3+kx)*4 + icc; lane l holds W2[oc=l&31][icc*16+(l>>5)*8 + t]
//    at taps (ky,kx), t=0..7 -> 16B per (kc,lane). Total 36 KB.
// ---------------------------------------------------------------------------
__global__ __launch_bounds__(256) void w2pack_kernel(
    const float* __restrict__ W2, ushort* __restrict__ w2b) {
  const int j = blockIdx.x * 256 + threadIdx.x;
  if (j >= 36 * 64) return;
  const int kc = j >> 6, lane = j & 63;
  const int tap = kc >> 2, icc = kc & 3;
  const int oc = lane & 31, icb = icc * 16 + (lane >> 5) * 8;
  ushort v[8];
#pragma unroll
  for (int t = 0; t < 8; ++t) v[t] = f2bf(W2[oc * 576 + (icb + t) * 9 + tap]);
  uint4 u;
  u.x = v[0] | ((uint)v[1] << 16); u.y = v[2] | ((uint)v[3] << 16);
  u.z = v[4] | ((uint)v[5] << 16); u.w = v[6] | ((uint)v[7] << 16);
  *reinterpret_cast<uint4*>(w2b + j * 8) = u;
}

// ---------------------------------------------------------------------------
// 4) conv12 MFMA: conv1 (fp32 VALU) -> bf16 LDS [pix][64ic] (XOR swizzle) ->
//    conv2 as implicit GEMM via v_mfma_f32_32x32x16_bf16.
//    Tile 2 rows x 64 cols; wave w: y_local=w>>1, x-half=w&1 (M=32 pixels).
//    K = 576 ordered (ky,kx,icc): A-frag = 1 ds_read_b128, B-frag = 1 global
//    b128 from pre-packed w2b (L2-resident). Epilogue: per-wave LDS transpose
//    -> coalesced fp32 stores with bias+relu. No atomics.
// ---------------------------------------------------------------------------
__global__ __launch_bounds__(256, 4) void conv12_kernel(
    const float* __restrict__ hlin, const float* __restrict__ W1,
    const float* __restrict__ b1, const ushort* __restrict__ w2b,
    const float* __restrict__ b2, float* __restrict__ h2) {
  __shared__ float s_h[6][68];            // hlin rows y0-2..y0+3
  __shared__ float s_w1[576 + 64];        // W1 + b1
  __shared__ __align__(16) char s_in[264 * 128];  // conv1 out bf16 [pix][ic]
  const int x0 = blockIdx.x * 64;
  const int y0 = blockIdx.y * 2;
  const int tid = threadIdx.x;
  const int lane = tid & 63;
  const int w = tid >> 6;
  const int m = lane & 31, hh = lane >> 5;

  for (int idx = tid; idx < 6 * 68; idx += 256) {
    const int r = idx / 68, xx = idx - r * 68;
    const int gy = y0 - 2 + r, gx = x0 - 2 + xx;
    s_h[r][xx] = (gy >= 0 && gy < NN && gx >= 0 && gx < 1024)
                     ? hlin[gy * 1024 + gx] : 0.f;
  }
  for (int idx = tid; idx < 640; idx += 256)
    s_w1[idx] = (idx < 576) ? W1[idx] : b1[idx - 576];
  __syncthreads();

  // conv1 phase: wave w covers ic-groups {w, w+4} (8 ic each) over 264 pixels
  // (rows y0-1..y0+2, cols x0-1..x0+64). Padding positions -> exact 0 (R3!).
  for (int gi = 0; gi < 2; ++gi) {
    const int g = w + gi * 4;
    float wr[72], br[8];
#pragma unroll
    for (int i = 0; i < 8; ++i) {
      br[i] = s_w1[576 + g * 8 + i];
#pragma unroll
      for (int t = 0; t < 9; ++t) wr[i * 9 + t] = s_w1[(g * 8 + i) * 9 + t];
    }
    for (int p0 = 0; p0 < 264; p0 += 64) {
      const int p = p0 + lane;
      if (p < 264) {
        const int ry = p / 66, rx = p - ry * 66;
        const int gy = y0 - 1 + ry, gx = x0 - 1 + rx;
        const bool inb = (gy >= 0) && (gy < NN) && (gx >= 0) && (gx < 1024);
        float sh[9];
#pragma unroll
        for (int dy = 0; dy < 3; ++dy)
#pragma unroll
          for (int dx = 0; dx < 3; ++dx) sh[dy * 3 + dx] = s_h[ry + dy][rx + dx];
        ushort ov[8];
#pragma unroll
        for (int i = 0; i < 8; ++i) {
          float a = br[i];
#pragma unroll
          for (int t = 0; t < 9; ++t) a += sh[t] * wr[i * 9 + t];
          a = inb ? fmaxf(a, 0.f) : 0.f;
          ov[i] = f2bf(a);
        }
        uint4 u;
        u.x = ov[0] | ((uint)ov[1] << 16); u.y = ov[2] | ((uint)ov[3] << 16);
        u.z = ov[4] | ((uint)ov[5] << 16); u.w = ov[6] | ((uint)ov[7] << 16);
        const int off = p * 128 + ((g * 16) ^ ((p & 7) << 4));
        *reinterpret_cast<uint4*>(s_in + off) = u;
      }
    }
  }
  __syncthreads();

  // MFMA phase
  const int yl = w >> 1, xh = w & 1;
  f32x16 acc = {};
#pragma unroll
  for (int ky = 0; ky < 3; ++ky)
#pragma unroll
    for (int kx = 0; kx < 3; ++kx)
#pragma unroll
      for (int icc = 0; icc < 4; ++icc) {
        const int pix = (yl + ky) * 66 + xh * 32 + kx + m;
        const int aoff = pix * 128 + ((icc * 32 + hh * 16) ^ ((pix & 7) << 4));
        const short8 af = *reinterpret_cast<const short8*>(s_in + aoff);
        const int kc = (ky * 3 + kx) * 4 + icc;
        const short8 bf = *reinterpret_cast<const short8*>(
            reinterpret_cast<const char*>(w2b) + (kc * 64 + lane) * 16);
        acc = __builtin_amdgcn_mfma_f32_32x32x16_bf16(af, bf, acc, 0, 0, 0);
      }

  // epilogue: transpose in per-wave LDS slice (reuse s_in), coalesced store
  __syncthreads();  // all waves done reading s_in
  float* reg = reinterpret_cast<float*>(s_in + w * 4096);
#pragma unroll
  for (int r = 0; r < 16; ++r) {
    const int row = (r & 3) + 8 * (r >> 2) + 4 * hh;  // pixel-in-tile (x)
    reg[row * 32 + (m ^ row)] = acc[r];               // oc = m
  }
  const int y = y0 + yl;
  if (y < NN) {
    const int xg = x0 + xh * 32;
#pragma unroll
    for (int t = 0; t < 16; ++t) {
      const int oc = t * 2 + hh;
      const float v = reg[m * 32 + (oc ^ m)];  // x = m
      h2[oc * NPIX + y * 1024 + xg + m] = fmaxf(v + b2[oc], 0.f);
    }
  }
}

// ---------------------------------------------------------------------------
// 5) conv3 (32->1) + relu -> out (h2 already relu'd; fmax on load harmless)
// ---------------------------------------------------------------------------
__global__ __launch_bounds__(256) void conv3_kernel(
    const float* __restrict__ h2, const float* __restrict__ W3,
    const float* __restrict__ b3, float* __restrict__ out) {
  __shared__ float s_in[32][6][66];
  __shared__ float s_w3[288];
  const int x0 = blockIdx.x * 64;
  const int y0 = blockIdx.y * 4;
  const int tid = threadIdx.x;
  const int ty = tid >> 6, tx = tid & 63;
  for (int idx = tid; idx < 288; idx += 256) s_w3[idx] = W3[idx];
  for (int idx = tid; idx < 32 * 6 * 66; idx += 256) {
    const int c = idx / 396;
    const int rem = idx - c * 396;
    const int r = rem / 66, xx = rem - r * 66;
    const int gy = y0 - 1 + r, gx = x0 - 1 + xx;
    s_in[c][r][xx] = (gy >= 0 && gy < NN && gx >= 0 && gx < 1024)
                         ? fmaxf(h2[c * NPIX + gy * 1024 + gx], 0.f) : 0.f;
  }
  __syncthreads();
  const int y = y0 + ty, x = x0 + tx;
  float acc = b3[0];
  for (int c = 0; c < 32; ++c) {
#pragma unroll
    for (int k = 0; k < 9; ++k)
      acc += s_in[c][ty + k / 3][tx + k % 3] * s_w3[c * 9 + k];
  }
  if (y < NN) out[y * 1024 + x] = fmaxf(acc, 0.f);
}

// ---------------------------------------------------------------------------
extern "C" void kernel_launch(void* const* d_in, const int* in_sizes, int n_in,
                              void* d_out, int out_size, void* d_ws, size_t ws_size,
                              hipStream_t stream) {
  const float* input = (const float*)d_in[0];
  const int*   src   = (const int*)d_in[1];
  const int*   dst   = (const int*)d_in[2];
  const float* W_lin = (const float*)d_in[3];
  const float* b_lin = (const float*)d_in[4];
  const float* W1    = (const float*)d_in[5];
  const float* b1    = (const float*)d_in[6];
  const float* W2    = (const float*)d_in[7];
  const float* b2    = (const float*)d_in[8];
  const float* W3    = (const float*)d_in[9];
  const float* b3    = (const float*)d_in[10];
  float* out = (float*)d_out;

  // ws (floats): hsum | hlin | w2b(9216 slots) | h2(32*NPIX) ~= 23.6 MB
  // gemm partials (8*NPIX) alias h2 (reduce done before conv12 writes h2)
  float*  hsum = (float*)d_ws;
  float*  hlin = hsum + NPIX;
  ushort* w2b  = (ushort*)(hlin + NPIX);
  float*  h2   = hlin + NPIX + 9216;
  float*  gpart = h2;

  segsum_kernel<<<dim3(NN, 4), 256, 0, stream>>>(input, src, dst, hsum);
  gemm_kernel<<<dim3(16, 6, KSPLIT), 256, 0, stream>>>(hsum, W_lin, gpart);
  w2pack_kernel<<<9, 256, 0, stream>>>(W2, w2b);
  reduce_kernel<<<NPIX / 256, 256, 0, stream>>>(gpart, b_lin, hlin);
  conv12_kernel<<<dim3(16, 85), 256, 0, stream>>>(hlin, W1, b1, w2b, b2, h2);
  conv3_kernel<<<dim3(16, 43), 256, 0, stream>>>(h2, W3, b3, out);
}

// Round 16
// 146.708 us; speedup vs baseline: 2.6573x; 1.1019x over previous
//
#include <hip/hip_runtime.h>
#include <hip/hip_bf16.h>

#define NN 169
#define NE 5408
#define F 1024
#define NPIX (NN * F)  // 173056

typedef short short8 __attribute__((ext_vector_type(8)));
typedef float f32x16 __attribute__((ext_vector_type(16)));

// RTNE float -> bf16 (bit-level; values finite)
__device__ __forceinline__ ushort f2bf(float f) {
  uint x = __float_as_uint(f);
  return (ushort)((x + 0x7FFFu + ((x >> 16) & 1u)) >> 16);
}

// ---------------------------------------------------------------------------
// 1) segment_sum   grid (169, 4)
// ---------------------------------------------------------------------------
__global__ __launch_bounds__(256) void segsum_kernel(
    const float* __restrict__ input, const int* __restrict__ src,
    const int* __restrict__ dst, float* __restrict__ hsum) {
  __shared__ int s_list[NE];
  __shared__ int s_count;
  const int node = blockIdx.x;
  const int fbase = blockIdx.y * 256;
  const int tid = threadIdx.x;
  if (tid == 0) s_count = 0;
  __syncthreads();
  for (int e = tid; e < NE; e += 256) {
    if (dst[e] == node) {
      int p = atomicAdd(&s_count, 1);
      s_list[p] = src[e];
    }
  }
  __syncthreads();
  const int cnt = s_count;
  const int f = fbase + tid;
  float acc = 0.f;
  for (int i = 0; i < cnt; ++i) acc += input[s_list[i] * F + f];
  hsum[node * F + f] = acc;
}

// ---------------------------------------------------------------------------
// 2) gemm split-K (BM=32, BN=64, 8 chunks of 128)  grid (16,6,8)
// ---------------------------------------------------------------------------
#define KSPLIT 8
#define KCHUNK (1024 / KSPLIT)
__global__ __launch_bounds__(256) void gemm_kernel(
    const float* __restrict__ A, const float* __restrict__ W,
    float* __restrict__ gpart) {
  __shared__ float As[16][33];
  __shared__ float Bs[16][68];
  const int n0 = blockIdx.x * 64;
  const int m0 = blockIdx.y * 32;
  const int kz = blockIdx.z;
  const int tid = threadIdx.x;
  const int tx = tid & 15;
  const int ty = tid >> 4;
  const int ar = tid >> 3, ak = (tid & 7) * 2;
  const int br = tid >> 2, bk = (tid & 3) * 4;
  float acc[2][4] = {};
  for (int k0 = kz * KCHUNK; k0 < (kz + 1) * KCHUNK; k0 += 16) {
    float2 av = make_float2(0.f, 0.f);
    if (m0 + ar < NN)
      av = *reinterpret_cast<const float2*>(&A[(m0 + ar) * F + k0 + ak]);
    As[ak][ar] = av.x; As[ak + 1][ar] = av.y;
    float4 bv = *reinterpret_cast<const float4*>(&W[(n0 + br) * F + k0 + bk]);
    Bs[bk][br] = bv.x; Bs[bk + 1][br] = bv.y;
    Bs[bk + 2][br] = bv.z; Bs[bk + 3][br] = bv.w;
    __syncthreads();
#pragma unroll
    for (int k = 0; k < 16; ++k) {
      const float a0 = As[k][ty * 2], a1 = As[k][ty * 2 + 1];
      const float4 b = *reinterpret_cast<const float4*>(&Bs[k][tx * 4]);
      acc[0][0] += a0 * b.x; acc[0][1] += a0 * b.y;
      acc[0][2] += a0 * b.z; acc[0][3] += a0 * b.w;
      acc[1][0] += a1 * b.x; acc[1][1] += a1 * b.y;
      acc[1][2] += a1 * b.z; acc[1][3] += a1 * b.w;
    }
    __syncthreads();
  }
#pragma unroll
  for (int i = 0; i < 2; ++i) {
    const int m = m0 + ty * 2 + i;
    if (m < NN)
      *reinterpret_cast<float4*>(&gpart[kz * NPIX + m * F + n0 + tx * 4]) =
          make_float4(acc[i][0], acc[i][1], acc[i][2], acc[i][3]);
  }
}

__global__ __launch_bounds__(256) void reduce_kernel(
    const float* __restrict__ gpart, const float* __restrict__ bias,
    float* __restrict__ hlin) {
  const int i = blockIdx.x * 256 + threadIdx.x;
  float a = 0.f;
#pragma unroll
  for (int z = 0; z < KSPLIT; ++z) a += gpart[z * NPIX + i];
  hlin[i] = a + bias[i & (F - 1)];
}

// ---------------------------------------------------------------------------
// 3) pack W2 into bf16 MFMA B-fragments for 32x32x16 (36 chunks x 64 lanes)
// ---------------------------------------------------------------------------
__global__ __launch_bounds__(256) void w2pack_kernel(
    const float* __restrict__ W2, ushort* __restrict__ w2b) {
  const int j = blockIdx.x * 256 + threadIdx.x;
  if (j >= 36 * 64) return;
  const int kc = j >> 6, lane = j & 63;
  const int tap = kc >> 2, icc = kc & 3;
  const int oc = lane & 31, icb = icc * 16 + (lane >> 5) * 8;
  ushort v[8];
#pragma unroll
  for (int t = 0; t < 8; ++t) v[t] = f2bf(W2[oc * 576 + (icb + t) * 9 + tap]);
  uint4 u;
  u.x = v[0] | ((uint)v[1] << 16); u.y = v[2] | ((uint)v[3] << 16);
  u.z = v[4] | ((uint)v[5] << 16); u.w = v[6] | ((uint)v[7] << 16);
  *reinterpret_cast<uint4*>(w2b + j * 8) = u;
}

// ---------------------------------------------------------------------------
// 4) conv12 MFMA: conv1 (fp32 VALU) -> bf16 LDS [pix][64ic] (XOR swizzle) ->
//    conv2 implicit GEMM via v_mfma_f32_32x32x16_bf16 -> h2 bf16 [pix][32oc].
// ---------------------------------------------------------------------------
__global__ __launch_bounds__(256, 4) void conv12_kernel(
    const float* __restrict__ hlin, const float* __restrict__ W1,
    const float* __restrict__ b1, const ushort* __restrict__ w2b,
    const float* __restrict__ b2, ushort* __restrict__ h2b) {
  __shared__ float s_h[6][68];              // hlin rows y0-2..y0+3
  __shared__ float s_w1[576 + 64 + 32];     // W1 + b1 + b2
  __shared__ __align__(16) char s_in[264 * 128];  // conv1 out bf16 [pix][ic]
  const int x0 = blockIdx.x * 64;
  const int y0 = blockIdx.y * 2;
  const int tid = threadIdx.x;
  const int lane = tid & 63;
  const int w = tid >> 6;
  const int m = lane & 31, hh = lane >> 5;

  for (int idx = tid; idx < 6 * 68; idx += 256) {
    const int r = idx / 68, xx = idx - r * 68;
    const int gy = y0 - 2 + r, gx = x0 - 2 + xx;
    s_h[r][xx] = (gy >= 0 && gy < NN && gx >= 0 && gx < 1024)
                     ? hlin[gy * 1024 + gx] : 0.f;
  }
  for (int idx = tid; idx < 672; idx += 256)
    s_w1[idx] = (idx < 576) ? W1[idx]
                            : (idx < 640 ? b1[idx - 576] : b2[idx - 640]);
  __syncthreads();

  // conv1 phase: wave w covers ic-groups {w, w+4} (8 ic each) over 264 pixels
  // (rows y0-1..y0+2, cols x0-1..x0+64). Padding positions -> exact 0 (R3!).
  for (int gi = 0; gi < 2; ++gi) {
    const int g = w + gi * 4;
    float wr[72], br[8];
#pragma unroll
    for (int i = 0; i < 8; ++i) {
      br[i] = s_w1[576 + g * 8 + i];
#pragma unroll
      for (int t = 0; t < 9; ++t) wr[i * 9 + t] = s_w1[(g * 8 + i) * 9 + t];
    }
    for (int p0 = 0; p0 < 264; p0 += 64) {
      const int p = p0 + lane;
      if (p < 264) {
        const int ry = p / 66, rx = p - ry * 66;
        const int gy = y0 - 1 + ry, gx = x0 - 1 + rx;
        const bool inb = (gy >= 0) && (gy < NN) && (gx >= 0) && (gx < 1024);
        float sh[9];
#pragma unroll
        for (int dy = 0; dy < 3; ++dy)
#pragma unroll
          for (int dx = 0; dx < 3; ++dx) sh[dy * 3 + dx] = s_h[ry + dy][rx + dx];
        ushort ov[8];
#pragma unroll
        for (int i = 0; i < 8; ++i) {
          float a = br[i];
#pragma unroll
          for (int t = 0; t < 9; ++t) a += sh[t] * wr[i * 9 + t];
          a = inb ? fmaxf(a, 0.f) : 0.f;
          ov[i] = f2bf(a);
        }
        uint4 u;
        u.x = ov[0] | ((uint)ov[1] << 16); u.y = ov[2] | ((uint)ov[3] << 16);
        u.z = ov[4] | ((uint)ov[5] << 16); u.w = ov[6] | ((uint)ov[7] << 16);
        const int off = p * 128 + ((g * 16) ^ ((p & 7) << 4));
        *reinterpret_cast<uint4*>(s_in + off) = u;
      }
    }
  }
  __syncthreads();

  // MFMA phase: wave w -> row yl = w>>1, x-half xh = w&1 (M=32 pixels)
  const int yl = w >> 1, xh = w & 1;
  f32x16 acc = {};
#pragma unroll
  for (int ky = 0; ky < 3; ++ky)
#pragma unroll
    for (int kx = 0; kx < 3; ++kx)
#pragma unroll
      for (int icc = 0; icc < 4; ++icc) {
        const int pix = (yl + ky) * 66 + xh * 32 + kx + m;
        const int aoff = pix * 128 + ((icc * 32 + hh * 16) ^ ((pix & 7) << 4));
        const short8 af = *reinterpret_cast<const short8*>(s_in + aoff);
        const int kc = (ky * 3 + kx) * 4 + icc;
        const short8 bf = *reinterpret_cast<const short8*>(
            reinterpret_cast<const char*>(w2b) + (kc * 64 + lane) * 16);
        acc = __builtin_amdgcn_mfma_f32_32x32x16_bf16(af, bf, acc, 0, 0, 0);
      }

  // epilogue: per-wave LDS transpose -> bf16 [pix][32oc] coalesced stores
  __syncthreads();  // all waves done reading s_in
  float* reg = reinterpret_cast<float*>(s_in + w * 4096);
#pragma unroll
  for (int r = 0; r < 16; ++r) {
    const int row = (r & 3) + 8 * (r >> 2) + 4 * hh;  // pixel-in-tile
    reg[row * 32 + (m ^ row)] = acc[r];               // oc = m
  }
  const int y = y0 + yl;
  if (y < NN) {
    const int pixg = y * 1024 + x0 + xh * 32 + m;  // this thread's pixel
    uint u[8];
#pragma unroll
    for (int jj = 0; jj < 8; ++jj) {
      const int oc0 = hh * 16 + jj * 2;
      const float v0 = fmaxf(reg[m * 32 + (oc0 ^ m)] + s_w1[640 + oc0], 0.f);
      const float v1 =
          fmaxf(reg[m * 32 + ((oc0 + 1) ^ m)] + s_w1[640 + oc0 + 1], 0.f);
      u[jj] = (uint)f2bf(v0) | ((uint)f2bf(v1) << 16);
    }
    uint4* dst4 = reinterpret_cast<uint4*>(h2b + pixg * 32 + hh * 16);
    dst4[0] = make_uint4(u[0], u[1], u[2], u[3]);
    dst4[1] = make_uint4(u[4], u[5], u[6], u[7]);
  }
}

// ---------------------------------------------------------------------------
// 5) conv3 (32->1) + relu from bf16 interleaved h2 [pix][32oc].
//    Tile 4x64; LDS 6x66 pixels x 64B, chunk-XOR-swizzled.
// ---------------------------------------------------------------------------
__global__ __launch_bounds__(256) void conv3_kernel(
    const ushort* __restrict__ h2b, const float* __restrict__ W3,
    const float* __restrict__ b3, float* __restrict__ out) {
  __shared__ __align__(16) ushort s_t[396 * 32];  // 25.3 KB
  __shared__ float s_w3[9][32];
  const int x0 = blockIdx.x * 64;
  const int y0 = blockIdx.y * 4;
  const int tid = threadIdx.x;
  const int ty = tid >> 6, tx = tid & 63;
  // R12 BUG FIX: 288 elements > 256 threads -- MUST be a strided loop.
  // (The `if (tid < 288)` guard left s_w3[8][*] uninitialized: tap ky=2,kx=2
  //  multiplied LDS garbage -> absmax 784.)
  for (int idx = tid; idx < 288; idx += 256)
    s_w3[idx >> 5][idx & 31] = W3[(idx & 31) * 9 + (idx >> 5)];
  for (int idx = tid; idx < 396 * 4; idx += 256) {
    const int p = idx >> 2, c = idx & 3;
    const int r = p / 66, xx = p - r * 66;
    const int gy = y0 - 1 + r, gx = x0 - 1 + xx;
    uint4 u = make_uint4(0, 0, 0, 0);
    if (gy >= 0 && gy < NN && gx >= 0 && gx < 1024)
      u = *reinterpret_cast<const uint4*>(h2b + (gy * 1024 + gx) * 32 + c * 8);
    *reinterpret_cast<uint4*>(s_t + p * 32 + ((c ^ (p & 3)) * 8)) = u;
  }
  __syncthreads();
  float acc = b3[0];
#pragma unroll
  for (int ky = 0; ky < 3; ++ky)
#pragma unroll
    for (int kx = 0; kx < 3; ++kx) {
      const int p = (ty + ky) * 66 + tx + kx;
      const float* wrow = s_w3[ky * 3 + kx];
#pragma unroll
      for (int c = 0; c < 4; ++c) {
        const uint4 u =
            *reinterpret_cast<const uint4*>(s_t + p * 32 + ((c ^ (p & 3)) * 8));
        const uint uu[4] = {u.x, u.y, u.z, u.w};
#pragma unroll
        for (int q = 0; q < 4; ++q) {
          acc += __uint_as_float(uu[q] << 16) * wrow[c * 8 + q * 2];
          acc += __uint_as_float(uu[q] & 0xffff0000u) * wrow[c * 8 + q * 2 + 1];
        }
      }
    }
  const int y = y0 + ty, x = x0 + tx;
  if (y < NN) out[y * 1024 + x] = fmaxf(acc, 0.f);
}

// ---------------------------------------------------------------------------
extern "C" void kernel_launch(void* const* d_in, const int* in_sizes, int n_in,
                              void* d_out, int out_size, void* d_ws, size_t ws_size,
                              hipStream_t stream) {
  const float* input = (const float*)d_in[0];
  const int*   src   = (const int*)d_in[1];
  const int*   dst   = (const int*)d_in[2];
  const float* W_lin = (const float*)d_in[3];
  const float* b_lin = (const float*)d_in[4];
  const float* W1    = (const float*)d_in[5];
  const float* b1    = (const float*)d_in[6];
  const float* W2    = (const float*)d_in[7];
  const float* b2    = (const float*)d_in[8];
  const float* W3    = (const float*)d_in[9];
  const float* b3    = (const float*)d_in[10];
  float* out = (float*)d_out;

  // ws (floats): hsum | hlin | w2b | {gpart(8*NPIX f32) alias h2b(32*NPIX bf16)}
  float*  hsum  = (float*)d_ws;
  float*  hlin  = hsum + NPIX;
  ushort* w2b   = (ushort*)(hlin + NPIX);
  float*  gpart = hlin + NPIX + 9216;
  ushort* h2b   = (ushort*)gpart;  // alias: gemm/reduce done before conv12

  segsum_kernel<<<dim3(NN, 4), 256, 0, stream>>>(input, src, dst, hsum);
  gemm_kernel<<<dim3(16, 6, KSPLIT), 256, 0, stream>>>(hsum, W_lin, gpart);
  w2pack_kernel<<<9, 256, 0, stream>>>(W2, w2b);
  reduce_kernel<<<NPIX / 256, 256, 0, stream>>>(gpart, b_lin, hlin);
  conv12_kernel<<<dim3(16, 85), 256, 0, stream>>>(hlin, W1, b1, w2b, b2, h2b);
  conv3_kernel<<<dim3(16, 43), 256, 0, stream>>>(h2b, W3, b3, out);
}

// Round 17
// 140.551 us; speedup vs baseline: 2.7737x; 1.0438x over previous
//
#include <hip/hip_runtime.h>
#include <hip/hip_bf16.h>

#define NN 169
#define NE 5408
#define F 1024
#define NPIX (NN * F)  // 173056

typedef short short8 __attribute__((ext_vector_type(8)));
typedef float f32x16 __attribute__((ext_vector_type(16)));

// RTNE float -> bf16 (bit-level; values finite)
__device__ __forceinline__ ushort f2bf(float f) {
  uint x = __float_as_uint(f);
  return (ushort)((x + 0x7FFFu + ((x >> 16) & 1u)) >> 16);
}

// ---------------------------------------------------------------------------
// 1) segment_sum -> bf16   grid (169, 4)
// ---------------------------------------------------------------------------
__global__ __launch_bounds__(256) void segsum_kernel(
    const float* __restrict__ input, const int* __restrict__ src,
    const int* __restrict__ dst, ushort* __restrict__ hsb) {
  __shared__ int s_list[NE];
  __shared__ int s_count;
  const int node = blockIdx.x;
  const int fbase = blockIdx.y * 256;
  const int tid = threadIdx.x;
  if (tid == 0) s_count = 0;
  __syncthreads();
  for (int e = tid; e < NE; e += 256) {
    if (dst[e] == node) {
      int p = atomicAdd(&s_count, 1);
      s_list[p] = src[e];
    }
  }
  __syncthreads();
  const int cnt = s_count;
  const int f = fbase + tid;
  float acc = 0.f;
  for (int i = 0; i < cnt; ++i) acc += input[s_list[i] * F + f];
  hsb[node * F + f] = f2bf(acc);
}

// ---------------------------------------------------------------------------
// 2) pack: W2 -> w2b MFMA B-frags (threads 0..2303, = blocks 0..8 exactly)
//          W_lin -> wlb MFMA B-frags (threads 2304.., clean block split)
//    wlb frag (nb,kc,lane): W_lin[nb*32+(lane&31)][kc*16+(lane>>5)*8 + j]
// ---------------------------------------------------------------------------
__global__ __launch_bounds__(256) void pack_kernel(
    const float* __restrict__ W2, const float* __restrict__ W_lin,
    ushort* __restrict__ w2b, ushort* __restrict__ wlb) {
  const int t = blockIdx.x * 256 + threadIdx.x;
  if (t < 2304) {
    const int kc = t >> 6, lane = t & 63;
    const int tap = kc >> 2, icc = kc & 3;
    const int oc = lane & 31, icb = icc * 16 + (lane >> 5) * 8;
    ushort v[8];
#pragma unroll
    for (int j = 0; j < 8; ++j) v[j] = f2bf(W2[oc * 576 + (icb + j) * 9 + tap]);
    uint4 u;
    u.x = v[0] | ((uint)v[1] << 16); u.y = v[2] | ((uint)v[3] << 16);
    u.z = v[4] | ((uint)v[5] << 16); u.w = v[6] | ((uint)v[7] << 16);
    *reinterpret_cast<uint4*>(w2b + t * 8) = u;
  } else {
    const int q = t - 2304;
    if (q >= 32 * 64 * 64) return;
    const int lane = q & 63;
    const int kc = (q >> 6) & 63;
    const int nb = q >> 12;
    const int nrow = nb * 32 + (lane & 31);
    const int kb = kc * 16 + (lane >> 5) * 8;
    const float4 a = *reinterpret_cast<const float4*>(&W_lin[nrow * F + kb]);
    const float4 b = *reinterpret_cast<const float4*>(&W_lin[nrow * F + kb + 4]);
    uint4 u;
    u.x = f2bf(a.x) | ((uint)f2bf(a.y) << 16);
    u.y = f2bf(a.z) | ((uint)f2bf(a.w) << 16);
    u.z = f2bf(b.x) | ((uint)f2bf(b.y) << 16);
    u.w = f2bf(b.z) | ((uint)f2bf(b.w) << 16);
    *reinterpret_cast<uint4*>(wlb + q * 8) = u;
  }
}

// ---------------------------------------------------------------------------
// 3) gemm2: hlin = hsum @ W_lin^T + b  via bf16 MFMA. grid (32 nb, 6 mt),
//    4 waves each own a K-quarter (16 MFMA); cross-wave reduce in LDS.
//    Operand/C-D layouts identical to the HW-validated conv12 usage.
// ---------------------------------------------------------------------------
__global__ __launch_bounds__(256) void gemm2_kernel(
    const ushort* __restrict__ hsb, const ushort* __restrict__ wlb,
    const float* __restrict__ bias, float* __restrict__ hlin) {
  __shared__ float red[4][64][17];  // 17-stride: conflict-free column reads
  const int n0 = blockIdx.x * 32;
  const int m0 = blockIdx.y * 32;
  const int tid = threadIdx.x;
  const int lane = tid & 63, w = tid >> 6;
  const int col = lane & 31, hi = lane >> 5;
  const bool arow_ok = (m0 + col) < NN;
  const ushort* abase = hsb + (m0 + col) * F + hi * 8;
  const ushort* bbase = wlb + ((blockIdx.x * 4096) + lane) * 8;
  f32x16 acc = {};
#pragma unroll
  for (int kc8 = 0; kc8 < 16; ++kc8) {
    const int kc = w * 16 + kc8;  // global 16-wide k-chunk
    short8 af = {};
    if (arow_ok) af = *reinterpret_cast<const short8*>(abase + kc * 16);
    const short8 bf = *reinterpret_cast<const short8*>(bbase + kc * 512);
    acc = __builtin_amdgcn_mfma_f32_32x32x16_bf16(af, bf, acc, 0, 0, 0);
  }
#pragma unroll
  for (int r = 0; r < 16; ++r) red[w][lane][r] = acc[r];
  __syncthreads();
  const float bn = bias[n0 + col];
#pragma unroll
  for (int rr = 0; rr < 4; ++rr) {
    const int r = w * 4 + rr;
    const float v = red[0][lane][r] + red[1][lane][r] + red[2][lane][r] +
                    red[3][lane][r];
    const int m = m0 + (r & 3) + 8 * (r >> 2) + 4 * hi;
    if (m < NN) hlin[m * F + n0 + col] = v + bn;
  }
}

// ---------------------------------------------------------------------------
// 4) conv12 MFMA: conv1 (fp32 VALU) -> bf16 LDS [pix][64ic] (XOR swizzle) ->
//    conv2 implicit GEMM via v_mfma_f32_32x32x16_bf16 -> h2 bf16 [pix][32oc].
// ---------------------------------------------------------------------------
__global__ __launch_bounds__(256, 4) void conv12_kernel(
    const float* __restrict__ hlin, const float* __restrict__ W1,
    const float* __restrict__ b1, const ushort* __restrict__ w2b,
    const float* __restrict__ b2, ushort* __restrict__ h2b) {
  __shared__ float s_h[6][68];              // hlin rows y0-2..y0+3
  __shared__ float s_w1[576 + 64 + 32];     // W1 + b1 + b2
  __shared__ __align__(16) char s_in[264 * 128];  // conv1 out bf16 [pix][ic]
  const int x0 = blockIdx.x * 64;
  const int y0 = blockIdx.y * 2;
  const int tid = threadIdx.x;
  const int lane = tid & 63;
  const int w = tid >> 6;
  const int m = lane & 31, hh = lane >> 5;

  for (int idx = tid; idx < 6 * 68; idx += 256) {
    const int r = idx / 68, xx = idx - r * 68;
    const int gy = y0 - 2 + r, gx = x0 - 2 + xx;
    s_h[r][xx] = (gy >= 0 && gy < NN && gx >= 0 && gx < 1024)
                     ? hlin[gy * 1024 + gx] : 0.f;
  }
  for (int idx = tid; idx < 672; idx += 256)
    s_w1[idx] = (idx < 576) ? W1[idx]
                            : (idx < 640 ? b1[idx - 576] : b2[idx - 640]);
  __syncthreads();

  // conv1 phase: wave w covers ic-groups {w, w+4} (8 ic each) over 264 pixels
  // (rows y0-1..y0+2, cols x0-1..x0+64). Padding positions -> exact 0 (R3!).
  for (int gi = 0; gi < 2; ++gi) {
    const int g = w + gi * 4;
    float wr[72], br[8];
#pragma unroll
    for (int i = 0; i < 8; ++i) {
      br[i] = s_w1[576 + g * 8 + i];
#pragma unroll
      for (int t = 0; t < 9; ++t) wr[i * 9 + t] = s_w1[(g * 8 + i) * 9 + t];
    }
    for (int p0 = 0; p0 < 264; p0 += 64) {
      const int p = p0 + lane;
      if (p < 264) {
        const int ry = p / 66, rx = p - ry * 66;
        const int gy = y0 - 1 + ry, gx = x0 - 1 + rx;
        const bool inb = (gy >= 0) && (gy < NN) && (gx >= 0) && (gx < 1024);
        float sh[9];
#pragma unroll
        for (int dy = 0; dy < 3; ++dy)
#pragma unroll
          for (int dx = 0; dx < 3; ++dx) sh[dy * 3 + dx] = s_h[ry + dy][rx + dx];
        ushort ov[8];
#pragma unroll
        for (int i = 0; i < 8; ++i) {
          float a = br[i];
#pragma unroll
          for (int t = 0; t < 9; ++t) a += sh[t] * wr[i * 9 + t];
          a = inb ? fmaxf(a, 0.f) : 0.f;
          ov[i] = f2bf(a);
        }
        uint4 u;
        u.x = ov[0] | ((uint)ov[1] << 16); u.y = ov[2] | ((uint)ov[3] << 16);
        u.z = ov[4] | ((uint)ov[5] << 16); u.w = ov[6] | ((uint)ov[7] << 16);
        const int off = p * 128 + ((g * 16) ^ ((p & 7) << 4));
        *reinterpret_cast<uint4*>(s_in + off) = u;
      }
    }
  }
  __syncthreads();

  // MFMA phase: wave w -> row yl = w>>1, x-half xh = w&1 (M=32 pixels)
  const int yl = w >> 1, xh = w & 1;
  f32x16 acc = {};
#pragma unroll
  for (int ky = 0; ky < 3; ++ky)
#pragma unroll
    for (int kx = 0; kx < 3; ++kx)
#pragma unroll
      for (int icc = 0; icc < 4; ++icc) {
        const int pix = (yl + ky) * 66 + xh * 32 + kx + m;
        const int aoff = pix * 128 + ((icc * 32 + hh * 16) ^ ((pix & 7) << 4));
        const short8 af = *reinterpret_cast<const short8*>(s_in + aoff);
        const int kc = (ky * 3 + kx) * 4 + icc;
        const short8 bf = *reinterpret_cast<const short8*>(
            reinterpret_cast<const char*>(w2b) + (kc * 64 + lane) * 16);
        acc = __builtin_amdgcn_mfma_f32_32x32x16_bf16(af, bf, acc, 0, 0, 0);
      }

  // epilogue: per-wave LDS transpose -> bf16 [pix][32oc] coalesced stores
  __syncthreads();  // all waves done reading s_in
  float* reg = reinterpret_cast<float*>(s_in + w * 4096);
#pragma unroll
  for (int r = 0; r < 16; ++r) {
    const int row = (r & 3) + 8 * (r >> 2) + 4 * hh;  // pixel-in-tile
    reg[row * 32 + (m ^ row)] = acc[r];               // oc = m
  }
  const int y = y0 + yl;
  if (y < NN) {
    const int pixg = y * 1024 + x0 + xh * 32 + m;  // this thread's pixel
    uint u[8];
#pragma unroll
    for (int jj = 0; jj < 8; ++jj) {
      const int oc0 = hh * 16 + jj * 2;
      const float v0 = fmaxf(reg[m * 32 + (oc0 ^ m)] + s_w1[640 + oc0], 0.f);
      const float v1 =
          fmaxf(reg[m * 32 + ((oc0 + 1) ^ m)] + s_w1[640 + oc0 + 1], 0.f);
      u[jj] = (uint)f2bf(v0) | ((uint)f2bf(v1) << 16);
    }
    uint4* dst4 = reinterpret_cast<uint4*>(h2b + pixg * 32 + hh * 16);
    dst4[0] = make_uint4(u[0], u[1], u[2], u[3]);
    dst4[1] = make_uint4(u[4], u[5], u[6], u[7]);
  }
}

// ---------------------------------------------------------------------------
// 5) conv3 (32->1) + relu from bf16 interleaved h2 [pix][32oc].
// ---------------------------------------------------------------------------
__global__ __launch_bounds__(256) void conv3_kernel(
    const ushort* __restrict__ h2b, const float* __restrict__ W3,
    const float* __restrict__ b3, float* __restrict__ out) {
  __shared__ __align__(16) ushort s_t[396 * 32];  // 25.3 KB
  __shared__ float s_w3[9][32];
  const int x0 = blockIdx.x * 64;
  const int y0 = blockIdx.y * 4;
  const int tid = threadIdx.x;
  const int ty = tid >> 6, tx = tid & 63;
  // R12 fix: 288 elements > 256 threads -- strided loop, not a guard.
  for (int idx = tid; idx < 288; idx += 256)
    s_w3[idx >> 5][idx & 31] = W3[(idx & 31) * 9 + (idx >> 5)];
  for (int idx = tid; idx < 396 * 4; idx += 256) {
    const int p = idx >> 2, c = idx & 3;
    const int r = p / 66, xx = p - r * 66;
    const int gy = y0 - 1 + r, gx = x0 - 1 + xx;
    uint4 u = make_uint4(0, 0, 0, 0);
    if (gy >= 0 && gy < NN && gx >= 0 && gx < 1024)
      u = *reinterpret_cast<const uint4*>(h2b + (gy * 1024 + gx) * 32 + c * 8);
    *reinterpret_cast<uint4*>(s_t + p * 32 + ((c ^ (p & 3)) * 8)) = u;
  }
  __syncthreads();
  float acc = b3[0];
#pragma unroll
  for (int ky = 0; ky < 3; ++ky)
#pragma unroll
    for (int kx = 0; kx < 3; ++kx) {
      const int p = (ty + ky) * 66 + tx + kx;
      const float* wrow = s_w3[ky * 3 + kx];
#pragma unroll
      for (int c = 0; c < 4; ++c) {
        const uint4 u =
            *reinterpret_cast<const uint4*>(s_t + p * 32 + ((c ^ (p & 3)) * 8));
        const uint uu[4] = {u.x, u.y, u.z, u.w};
#pragma unroll
        for (int q = 0; q < 4; ++q) {
          acc += __uint_as_float(uu[q] << 16) * wrow[c * 8 + q * 2];
          acc += __uint_as_float(uu[q] & 0xffff0000u) * wrow[c * 8 + q * 2 + 1];
        }
      }
    }
  const int y = y0 + ty, x = x0 + tx;
  if (y < NN) out[y * 1024 + x] = fmaxf(acc, 0.f);
}

// ---------------------------------------------------------------------------
extern "C" void kernel_launch(void* const* d_in, const int* in_sizes, int n_in,
                              void* d_out, int out_size, void* d_ws, size_t ws_size,
                              hipStream_t stream) {
  const float* input = (const float*)d_in[0];
  const int*   src   = (const int*)d_in[1];
  const int*   dst   = (const int*)d_in[2];
  const float* W_lin = (const float*)d_in[3];
  const float* b_lin = (const float*)d_in[4];
  const float* W1    = (const float*)d_in[5];
  const float* b1    = (const float*)d_in[6];
  const float* W2    = (const float*)d_in[7];
  const float* b2    = (const float*)d_in[8];
  const float* W3    = (const float*)d_in[9];
  const float* b3    = (const float*)d_in[10];
  float* out = (float*)d_out;

  // ws byte layout: hsb(346112) | hlin(692224) | w2b(36864) | wlb(2097152) |
  //                 h2b(11075584)  => ~14.2 MB
  char* base = (char*)d_ws;
  ushort* hsb  = (ushort*)(base);
  float*  hlin = (float*)(base + 346112);
  ushort* w2b  = (ushort*)(base + 1038336);
  ushort* wlb  = (ushort*)(base + 1075200);
  ushort* h2b  = (ushort*)(base + 3172352);

  segsum_kernel<<<dim3(NN, 4), 256, 0, stream>>>(input, src, dst, hsb);
  pack_kernel<<<521, 256, 0, stream>>>(W2, W_lin, w2b, wlb);
  gemm2_kernel<<<dim3(32, 6), 256, 0, stream>>>(hsb, wlb, b_lin, hlin);
  conv12_kernel<<<dim3(16, 85), 256, 0, stream>>>(hlin, W1, b1, w2b, b2, h2b);
  conv3_kernel<<<dim3(16, 43), 256, 0, stream>>>(h2b, W3, b3, out);
}